// Round 10
// baseline (133.147 us; speedup 1.0000x reference)
//
#include <hip/hip_runtime.h>
#include <hip/hip_bf16.h>

// NonlocalBlock: B=4, C=64, H=W=96 (N=9216), Ci=32, COMPRESSION=2 (M=4608).
// R15: kf-only prefetch on the R13 base (best: attn 53.4, total 129.4).
//      R14 (KVBLK=64) regressed -> reverted. Remaining theory: kf load-to-use
//      distance in R13 is only the 6-MFMA PV block (~50cy) vs ~200cy L2
//      latency -> S_STEP(0) stalls every iteration. R11 tested this but died
//      of spill at the 6-wave/EU reg cap; R13's bounds(256,4) has 70+ regs of
//      slack. Change: dual kf buffers (+8 VGPR), prefetch kf(i+1) at iteration
//      top, consume kf(i) loaded a full iteration (~800cy) earlier; vf stays
//      single (distance already ~600cy). 2x-unrolled loop for static parity.
//      Pass/fail gate: FETCH ~16.6MB / WRITE ~9.2MB / VGPR <= ~75 (no spill).

#define NQ 9216
#define MM 4608
#define TPW 36         // 32-m tiles per wave (MM / 4 waves / 32)
#define LOG2E 1.44269504088896340736f

typedef __attribute__((ext_vector_type(8))) short bf16x8;   // 8 bf16, 4 VGPRs
typedef __attribute__((ext_vector_type(4))) float f32x4;    // MFMA C/D
typedef __attribute__((ext_vector_type(4))) unsigned short u16x4;

static __device__ __forceinline__ unsigned pk2(float a, float b) {
    __hip_bfloat162 h = __float22bfloat162_rn(make_float2(a, b));
    return *reinterpret_cast<unsigned*>(&h);   // low16=a, high16=b
}

// ---------------------------------------------------------------------------
// Kernel 1: projections. 1152 blocks x 128 thr (2 waves, 1 n-tile of 16 each).
// theta pre-scaled by LOG2E; phi [m][ci]; gT [ci][m] via LDS transpose.
// ---------------------------------------------------------------------------
__global__ __launch_bounds__(128, 4) void proj_kernel(
    const float* __restrict__ x,
    const float* __restrict__ wt, const float* __restrict__ bt,
    const float* __restrict__ wp, const float* __restrict__ bp,
    const float* __restrict__ wg, const float* __restrict__ bg,
    unsigned short* __restrict__ theta, unsigned short* __restrict__ phi,
    unsigned short* __restrict__ gT)
{
    __shared__ unsigned short gst[32 * 20];   // [ci 32][m-local 16 +4]

    const int tid  = threadIdx.x;
    const int wid  = tid >> 6;
    const int lane = tid & 63;
    const int q = lane >> 4;
    const int c = lane & 15;

    const int b     = blockIdx.x / 288;
    const int rem   = blockIdx.x % 288;
    const int n0    = rem * 32 + wid * 16;

    const float* Wm[3] = {wt, wp, wg};
    const float* Bm[3] = {bt, bp, bg};

    bf16x8 wf[3][2][2];
    float bias[3][2];
#pragma unroll
    for (int p = 0; p < 3; ++p) {
#pragma unroll
        for (int ct = 0; ct < 2; ++ct) {
            bias[p][ct] = Bm[p][ct * 16 + c];
#pragma unroll
            for (int ks = 0; ks < 2; ++ks) {
                const float* wsrc = Wm[p] + (ct * 16 + c) * 64 + ks * 32 + q * 8;
                f32x4 w0 = *(const f32x4*)wsrc;
                f32x4 w1 = *(const f32x4*)(wsrc + 4);
                unsigned* wk = (unsigned*)&wf[p][ct][ks];
                wk[0] = pk2(w0[0], w0[1]); wk[1] = pk2(w0[2], w0[3]);
                wk[2] = pk2(w1[0], w1[1]); wk[3] = pk2(w1[2], w1[3]);
            }
        }
    }

    bf16x8 af[2];
#pragma unroll
    for (int ks = 0; ks < 2; ++ks) {
        unsigned* ap = (unsigned*)&af[ks];
#pragma unroll
        for (int j2 = 0; j2 < 4; ++j2) {
            float x0 = x[(b * 64 + ks * 32 + q * 8 + j2 * 2) * NQ + n0 + c];
            float x1 = x[(b * 64 + ks * 32 + q * 8 + j2 * 2 + 1) * NQ + n0 + c];
            ap[j2] = pk2(x0, x1);
        }
    }

#pragma unroll
    for (int p = 0; p < 3; ++p) {
#pragma unroll
        for (int ct = 0; ct < 2; ++ct) {
            f32x4 acc = {0.f, 0.f, 0.f, 0.f};
            acc = __builtin_amdgcn_mfma_f32_16x16x32_bf16(af[0], wf[p][ct][0], acc, 0, 0, 0);
            acc = __builtin_amdgcn_mfma_f32_16x16x32_bf16(af[1], wf[p][ct][1], acc, 0, 0, 0);
#pragma unroll
            for (int r = 0; r < 4; ++r) acc[r] += bias[p][ct];
            const int ci = ct * 16 + c;
            if (p == 0) {
                unsigned pv0 = pk2(acc[0] * LOG2E, acc[1] * LOG2E);
                unsigned pv1 = pk2(acc[2] * LOG2E, acc[3] * LOG2E);
                theta[(b * NQ + n0 + 4 * q + 0) * 32 + ci] = (unsigned short)pv0;
                theta[(b * NQ + n0 + 4 * q + 1) * 32 + ci] = (unsigned short)(pv0 >> 16);
                theta[(b * NQ + n0 + 4 * q + 2) * 32 + ci] = (unsigned short)pv1;
                theta[(b * NQ + n0 + 4 * q + 3) * 32 + ci] = (unsigned short)(pv1 >> 16);
            } else {
                unsigned pv = pk2(fmaxf(acc[0], acc[1]), fmaxf(acc[2], acc[3]));
                if (p == 1) {
                    const int m0 = (n0 >> 1) + 2 * q;
                    phi[(b * MM + m0) * 32 + ci]     = (unsigned short)pv;
                    phi[(b * MM + m0 + 1) * 32 + ci] = (unsigned short)(pv >> 16);
                } else {
                    // m-local = wid*8 + 2q + {0,1}
                    *(unsigned int*)(gst + ci * 20 + wid * 8 + 2 * q) = pv;
                }
            }
        }
    }

    __syncthreads();
    {   // coalesced gT store: 16 m x 32 ci
        const int ci = tid >> 2;
        const int m4 = (tid & 3) * 4;
        u16x4 v = *(const u16x4*)(gst + ci * 20 + m4);
        *(u16x4*)(gT + (b * 32 + ci) * MM + rem * 16 + m4) = v;
    }
}

// ---------------------------------------------------------------------------
// Kernel 2: attention + fused out-projection. Block = 4 waves m-splitting MM
// (1152 m each) for one 48-q-row tile (rt=3). R13's flash loop + kf dbuf:
// per iter: LOAD_KF(next) | PV(prev) | LOAD_VF(cur) | S(cur, kf loaded one
// full iteration ago). Single P buffer WAR-safe (same-wave in-order DS).
// Epilogue: overlay barrier; f32 slices -> union LDS; reduce + normalize ->
// yld bf16; fused out-projection with bias + residual.
// Grid: 768 blocks x 256 thr (3 blocks/CU).
// ---------------------------------------------------------------------------
__global__ __launch_bounds__(256, 4) void attn_kernel(
    const unsigned short* __restrict__ theta, const unsigned short* __restrict__ phi,
    const unsigned short* __restrict__ gT,
    const float* __restrict__ w_out, const float* __restrict__ b_out,
    const float* __restrict__ x, float* __restrict__ out)
{
    // Overlay: pld live during the flash loop; ep.* live only after the
    // post-loop barrier. max(12288, 31616) = 31616 B.
    __shared__ union SharedU {
        unsigned short pld[4][48 * 32];          // per-wave P^T [n 48][m 32], 3KB each
        struct {
            float red[4][48][36];                // per-wave acc [n][ci 32 +4pad]
            float lred[4][48];                   // per-wave lsum per n
            unsigned short yld[32][50];          // normalized y^T [ci][n 48+2]
        } ep;
    } sh;

    const int tid  = threadIdx.x;
    const int w    = tid >> 6;
    const int lane = tid & 63;
    const int q  = lane >> 4;
    const int c  = lane & 15;
    const int sw = ((c >> 1) & 3) << 3;   // XOR swizzle on the m short-index (16B chunks)

    const int b  = blockIdx.x / 192;
    const int nb = (blockIdx.x % 192) * 48;      // block's 48 q-rows (all 4 waves)

    // Q B-frags: theta[n][ch], lane col n = c (per rt tile), k = q*8+j
    bf16x8 qf[3];
#pragma unroll
    for (int rt = 0; rt < 3; ++rt)
        qf[rt] = *(const bf16x8*)(theta + (b * NQ + nb + rt * 16 + c) * 32 + q * 8);

    const unsigned short* phiB = phi + (size_t)b * MM * 32;
    const unsigned short* gTB  = gT + (size_t)b * 32 * MM;
    unsigned short* myp = sh.pld[w];

    f32x4 acc[3][2];    // [rt n-tile][s2 ci-tile]: col=n, row=ci
    float lsum[3];      // per-lane partial sum of exp values (col n = rt*16+c)
#pragma unroll
    for (int rt = 0; rt < 3; ++rt) {
        lsum[rt] = 0.f;
#pragma unroll
        for (int s2 = 0; s2 < 2; ++s2) acc[rt][s2] = (f32x4){0.f, 0.f, 0.f, 0.f};
    }

    const int t0 = w * TPW;    // this wave's first 32-m tile
    bf16x8 kfA[2], kfB[2], vf[2];

#define LOAD_KF(DST, m0) do {                                                 \
    DST[0] = *(const bf16x8*)(phiB + ((m0) + c) * 32 + q * 8);                \
    DST[1] = *(const bf16x8*)(phiB + ((m0) + 16 + c) * 32 + q * 8);           \
} while (0)

#define LOAD_VF(m0) do {                                                      \
    vf[0] = *(const bf16x8*)(gTB + c * MM + (m0) + q * 8);                    \
    vf[1] = *(const bf16x8*)(gTB + (16 + c) * MM + (m0) + q * 8);             \
} while (0)

// S(rt): 2 S-MFMAs + 8 exp2 + lsum adds + 4 cvt_pk + 2 ds_write_b64
#define S_STEP(rt, KF) do {                                                  \
    _Pragma("unroll")                                                        \
    for (int mct = 0; mct < 2; ++mct) {                                      \
        f32x4 z = {0.f, 0.f, 0.f, 0.f};                                      \
        f32x4 s = __builtin_amdgcn_mfma_f32_16x16x32_bf16(KF[mct], qf[rt], z, 0, 0, 0); \
        float e0 = __builtin_amdgcn_exp2f(s[0]);                             \
        float e1 = __builtin_amdgcn_exp2f(s[1]);                             \
        float e2 = __builtin_amdgcn_exp2f(s[2]);                             \
        float e3 = __builtin_amdgcn_exp2f(s[3]);                             \
        lsum[rt] += (e0 + e1) + (e2 + e3);                                   \
        uint2 hv = {pk2(e0, e1), pk2(e2, e3)};                               \
        *(uint2*)(myp + (((rt) * 16 + c) << 5) + ((mct * 16 + 4 * q) ^ sw)) = hv; \
    }                                                                        \
} while (0)

// PV(rt): 1 ds_read_b128 (full 32-m row) + 2 MFMAs
#define PV_STEP(rt) do {                                                     \
    bf16x8 pf = *(const bf16x8*)(myp + (((rt) * 16 + c) << 5) + ((q * 8) ^ sw)); \
    acc[rt][0] = __builtin_amdgcn_mfma_f32_16x16x32_bf16(vf[0], pf, acc[rt][0], 0, 0, 0); \
    acc[rt][1] = __builtin_amdgcn_mfma_f32_16x16x32_bf16(vf[1], pf, acc[rt][1], 0, 0, 0); \
} while (0)

    // ---- prologue: tile 0 loads + kf(1) prefetch, then S(0) ----
    LOAD_KF(kfA, t0 * 32);
    LOAD_VF(t0 * 32);
    LOAD_KF(kfB, (t0 + 1) * 32);
    S_STEP(0, kfA); S_STEP(1, kfA); S_STEP(2, kfA);

    // ---- steady state: 2x-unrolled for static buffer parity ----
    // odd mi consumes kfB (prefetch into kfA); even mi consumes kfA.
    for (int mi = 1; mi + 1 < TPW; mi += 2) {
        {   // mi (odd): kf current = kfB
            const int m0 = (t0 + mi) * 32;
            LOAD_KF(kfA, (t0 + mi + 1) * 32);     // prefetch tile mi+1
            PV_STEP(0); PV_STEP(1); PV_STEP(2);   // P(mi-1) x vf(mi-1)
            LOAD_VF(m0);                          // vf(mi), used next iter
            S_STEP(0, kfB); S_STEP(1, kfB); S_STEP(2, kfB);
        }
        {   // mi+1 (even): kf current = kfA
            const int m0 = (t0 + mi + 1) * 32;
            if (mi + 2 < TPW) LOAD_KF(kfB, (t0 + mi + 2) * 32);
            PV_STEP(0); PV_STEP(1); PV_STEP(2);
            LOAD_VF(m0);
            S_STEP(0, kfA); S_STEP(1, kfA); S_STEP(2, kfA);
        }
    }
    {   // final mi = TPW-1 (odd, 35): kf current = kfB, no prefetch
        const int m0 = (t0 + TPW - 1) * 32;
        PV_STEP(0); PV_STEP(1); PV_STEP(2);
        LOAD_VF(m0);
        S_STEP(0, kfB); S_STEP(1, kfB); S_STEP(2, kfB);
    }

    // ---- epilogue: PV of last tile ----
    PV_STEP(0); PV_STEP(1); PV_STEP(2);

#undef LOAD_KF
#undef LOAD_VF
#undef S_STEP
#undef PV_STEP

    // lsum: butterfly across the 4 q-groups -> totals in lanes 0..15
    float lv[3];
#pragma unroll
    for (int rt = 0; rt < 3; ++rt) {
        float v = lsum[rt];
        v += __shfl_xor(v, 16);
        v += __shfl_xor(v, 32);
        lv[rt] = v;
    }

    // ---- overlay safety: all pld reads done before ep.* writes ----
    __syncthreads();

    // ---- stage per-wave partial slices ----
    if (lane < 16) {
        sh.ep.lred[w][lane]      = lv[0];
        sh.ep.lred[w][16 + lane] = lv[1];
        sh.ep.lred[w][32 + lane] = lv[2];
    }
#pragma unroll
    for (int rt = 0; rt < 3; ++rt)
#pragma unroll
        for (int s2 = 0; s2 < 2; ++s2)
            *(f32x4*)&sh.ep.red[w][rt * 16 + c][s2 * 16 + 4 * q] = acc[rt][s2];

    __syncthreads();

    // ---- cross-wave sum + normalize -> yld bf16 [ci][n] ----
    if (tid < 192) {
        const int n   = tid % 48;            // 48 n
        const int cig = (tid / 48) * 8;      // 8 ci values per thread
        float ls = (sh.ep.lred[0][n] + sh.ep.lred[1][n]) +
                   (sh.ep.lred[2][n] + sh.ep.lred[3][n]);
        float inv = 1.0f / ls;
        f32x4 s0 = {0.f, 0.f, 0.f, 0.f}, s1 = {0.f, 0.f, 0.f, 0.f};
#pragma unroll
        for (int ww = 0; ww < 4; ++ww) {
            s0 += *(const f32x4*)&sh.ep.red[ww][n][cig];
            s1 += *(const f32x4*)&sh.ep.red[ww][n][cig + 4];
        }
#pragma unroll
        for (int k = 0; k < 4; ++k) {
            sh.ep.yld[cig + k][n]     = (unsigned short)(pk2(s0[k] * inv, 0.f) & 0xffff);
            sh.ep.yld[cig + 4 + k][n] = (unsigned short)(pk2(s1[k] * inv, 0.f) & 0xffff);
        }
    }
    __syncthreads();

    // ---- fused out-projection: wave w -> chn rows w*16..w*16+15 ----
    {
        bf16x8 wof;
        {
            const float* wsrc = w_out + (w * 16 + c) * 32 + q * 8;
            f32x4 w0 = *(const f32x4*)wsrc;
            f32x4 w1 = *(const f32x4*)(wsrc + 4);
            unsigned* wk = (unsigned*)&wof;
            wk[0] = pk2(w0[0], w0[1]); wk[1] = pk2(w0[2], w0[3]);
            wk[2] = pk2(w1[0], w1[1]); wk[3] = pk2(w1[2], w1[3]);
        }
#pragma unroll
        for (int nt = 0; nt < 3; ++nt) {
            bf16x8 yf;
            unsigned short* yp = (unsigned short*)&yf;
#pragma unroll
            for (int j = 0; j < 8; ++j)
                yp[j] = sh.ep.yld[q * 8 + j][nt * 16 + c];
            f32x4 z = {0.f, 0.f, 0.f, 0.f};
            f32x4 o = __builtin_amdgcn_mfma_f32_16x16x32_bf16(wof, yf, z, 0, 0, 0);
#pragma unroll
            for (int r = 0; r < 4; ++r) {
                const int chn = w * 16 + 4 * q + r;
                const size_t addr = (size_t)(b * 64 + chn) * NQ + nb + nt * 16 + c;
                out[addr] = o[r] + b_out[chn] + x[addr];
            }
        }
    }
}

extern "C" void kernel_launch(void* const* d_in, const int* in_sizes, int n_in,
                              void* d_out, int out_size, void* d_ws, size_t ws_size,
                              hipStream_t stream) {
    const float* x       = (const float*)d_in[0];
    const float* w_theta = (const float*)d_in[1];
    const float* b_theta = (const float*)d_in[2];
    const float* w_phi   = (const float*)d_in[3];
    const float* b_phi   = (const float*)d_in[4];
    const float* w_g     = (const float*)d_in[5];
    const float* b_g     = (const float*)d_in[6];
    const float* w_out   = (const float*)d_in[7];
    const float* b_out   = (const float*)d_in[8];
    float* out = (float*)d_out;

    // ws layout (bytes):
    //   theta bf16 [4][9216][32] : 2,359,296
    //   phi   bf16 [4][4608][32] : 1,179,648
    //   gT    bf16 [4][32][4608] : 1,179,648
    unsigned short* theta = (unsigned short*)d_ws;
    unsigned short* phi   = theta + 4 * NQ * 32;
    unsigned short* gT    = phi + 4 * MM * 32;

    proj_kernel<<<1152, 128, 0, stream>>>(x, w_theta, b_theta, w_phi, b_phi,
                                          w_g, b_g, theta, phi, gT);
    attn_kernel<<<768, 256, 0, stream>>>(theta, phi, gT, w_out, b_out, x, out);
}

// Round 12
// 124.807 us; speedup vs baseline: 1.0668x; 1.0668x over previous
//
#include <hip/hip_runtime.h>
#include <hip/hip_bf16.h>

// NonlocalBlock: B=4, C=64, H=W=96 (N=9216), Ci=32, COMPRESSION=2 (M=4608).
// R17: revert R16's cooperative fusion (launch silently failed under graph
//      capture -> zero output). Back to the R13 two-kernel structure (129.4us
//      best) with two independent, attributable improvements:
//      (a) attn: lsum via ones-row MFMA (R5/R10-proven) on the rt=3 base --
//          removes 18 VALU adds/iter + end butterfly from the 53%-busy VALU
//          pipe, +3 MFMA/iter on the 84%-idle matrix pipe; regs ~73 < 128 cap.
//      (b) proj: 32 n per wave (576 blocks x 128 thr, 2 sequential 16-n tiles
//          reusing wf/bias) -- halves the ~150-VALU per-wave setup per n.
//      Gate: FETCH ~16.6MB / WRITE ~9.2MB / VGPR <= 80 / absmax ~0.117.

#define NQ 9216
#define MM 4608
#define TPW 36         // 32-m tiles per wave (MM / 4 waves / 32)
#define LOG2E 1.44269504088896340736f

typedef __attribute__((ext_vector_type(8))) short bf16x8;   // 8 bf16, 4 VGPRs
typedef __attribute__((ext_vector_type(4))) float f32x4;    // MFMA C/D
typedef __attribute__((ext_vector_type(4))) unsigned short u16x4;

static __device__ __forceinline__ unsigned pk2(float a, float b) {
    __hip_bfloat162 h = __float22bfloat162_rn(make_float2(a, b));
    return *reinterpret_cast<unsigned*>(&h);   // low16=a, high16=b
}

// ---------------------------------------------------------------------------
// Kernel 1: projections. 576 blocks x 128 thr (2 waves, 32 n per wave via two
// sequential 16-n tiles reusing the weight fragments). theta pre-scaled by
// LOG2E; phi [m][ci]; gT [ci][m] via LDS transpose (32-m block tile).
// ---------------------------------------------------------------------------
__global__ __launch_bounds__(128, 4) void proj_kernel(
    const float* __restrict__ x,
    const float* __restrict__ wt, const float* __restrict__ bt,
    const float* __restrict__ wp, const float* __restrict__ bp,
    const float* __restrict__ wg, const float* __restrict__ bg,
    unsigned short* __restrict__ theta, unsigned short* __restrict__ phi,
    unsigned short* __restrict__ gT)
{
    __shared__ unsigned short gst[32 * 36];   // [ci 32][m-local 32 +4]

    const int tid  = threadIdx.x;
    const int wid  = tid >> 6;
    const int lane = tid & 63;
    const int q = lane >> 4;
    const int c = lane & 15;

    const int b   = blockIdx.x / 144;
    const int rem = blockIdx.x % 144;
    const int n0  = rem * 64 + wid * 32;     // this wave's 32 n-columns

    const float* Wm[3] = {wt, wp, wg};
    const float* Bm[3] = {bt, bp, bg};

    // weight fragments + bias: loaded ONCE, reused for both n-tiles
    bf16x8 wf[3][2][2];
    float bias[3][2];
#pragma unroll
    for (int p = 0; p < 3; ++p) {
#pragma unroll
        for (int ct = 0; ct < 2; ++ct) {
            bias[p][ct] = Bm[p][ct * 16 + c];
#pragma unroll
            for (int ks = 0; ks < 2; ++ks) {
                const float* wsrc = Wm[p] + (ct * 16 + c) * 64 + ks * 32 + q * 8;
                f32x4 w0 = *(const f32x4*)wsrc;
                f32x4 w1 = *(const f32x4*)(wsrc + 4);
                unsigned* wk = (unsigned*)&wf[p][ct][ks];
                wk[0] = pk2(w0[0], w0[1]); wk[1] = pk2(w0[2], w0[3]);
                wk[2] = pk2(w1[0], w1[1]); wk[3] = pk2(w1[2], w1[3]);
            }
        }
    }

#pragma unroll
    for (int nt = 0; nt < 2; ++nt) {
        const int n0t = n0 + nt * 16;

        bf16x8 af[2];
#pragma unroll
        for (int ks = 0; ks < 2; ++ks) {
            unsigned* ap = (unsigned*)&af[ks];
#pragma unroll
            for (int j2 = 0; j2 < 4; ++j2) {
                float x0 = x[(b * 64 + ks * 32 + q * 8 + j2 * 2) * NQ + n0t + c];
                float x1 = x[(b * 64 + ks * 32 + q * 8 + j2 * 2 + 1) * NQ + n0t + c];
                ap[j2] = pk2(x0, x1);
            }
        }

#pragma unroll
        for (int p = 0; p < 3; ++p) {
#pragma unroll
            for (int ct = 0; ct < 2; ++ct) {
                f32x4 acc = {0.f, 0.f, 0.f, 0.f};
                acc = __builtin_amdgcn_mfma_f32_16x16x32_bf16(af[0], wf[p][ct][0], acc, 0, 0, 0);
                acc = __builtin_amdgcn_mfma_f32_16x16x32_bf16(af[1], wf[p][ct][1], acc, 0, 0, 0);
#pragma unroll
                for (int r = 0; r < 4; ++r) acc[r] += bias[p][ct];
                const int ci = ct * 16 + c;
                if (p == 0) {
                    unsigned pv0 = pk2(acc[0] * LOG2E, acc[1] * LOG2E);
                    unsigned pv1 = pk2(acc[2] * LOG2E, acc[3] * LOG2E);
                    theta[(b * NQ + n0t + 4 * q + 0) * 32 + ci] = (unsigned short)pv0;
                    theta[(b * NQ + n0t + 4 * q + 1) * 32 + ci] = (unsigned short)(pv0 >> 16);
                    theta[(b * NQ + n0t + 4 * q + 2) * 32 + ci] = (unsigned short)pv1;
                    theta[(b * NQ + n0t + 4 * q + 3) * 32 + ci] = (unsigned short)(pv1 >> 16);
                } else {
                    unsigned pv = pk2(fmaxf(acc[0], acc[1]), fmaxf(acc[2], acc[3]));
                    if (p == 1) {
                        const int m0 = (n0t >> 1) + 2 * q;
                        phi[(b * MM + m0) * 32 + ci]     = (unsigned short)pv;
                        phi[(b * MM + m0 + 1) * 32 + ci] = (unsigned short)(pv >> 16);
                    } else {
                        // m-local (block) = wid*16 + nt*8 + 2q + {0,1}
                        *(unsigned int*)(gst + ci * 36 + wid * 16 + nt * 8 + 2 * q) = pv;
                    }
                }
            }
        }
    }

    __syncthreads();
    {   // coalesced gT store: 32 m x 32 ci (8 shorts per thread)
        const int ci = tid >> 2;
        const int m8 = (tid & 3) * 8;
        u16x4 v0 = *(const u16x4*)(gst + ci * 36 + m8);
        u16x4 v1 = *(const u16x4*)(gst + ci * 36 + m8 + 4);
        unsigned short* dst = gT + (size_t)(b * 32 + ci) * MM + rem * 32 + m8;
        *(u16x4*)dst       = v0;
        *(u16x4*)(dst + 4) = v1;
    }
}

// ---------------------------------------------------------------------------
// Kernel 2: attention + fused out-projection. Block = 4 waves m-splitting MM
// (1152 m each) for one 48-q-row tile (rt=3). R13's flash loop with lsum via
// ones-row MFMA (R5/R10-proven): PV(rt) gains 1 lsum-MFMA; S_STEP loses the
// 6 VALU adds; no end butterfly. Single P buffer WAR-safe (same-wave in-order
// DS). Epilogue: overlay barrier; f32 slices -> union LDS; reduce + normalize
// -> yld bf16; fused out-projection with bias + residual.
// Grid: 768 blocks x 256 thr (3 blocks/CU).
// ---------------------------------------------------------------------------
__global__ __launch_bounds__(256, 4) void attn_kernel(
    const unsigned short* __restrict__ theta, const unsigned short* __restrict__ phi,
    const unsigned short* __restrict__ gT,
    const float* __restrict__ w_out, const float* __restrict__ b_out,
    const float* __restrict__ x, float* __restrict__ out)
{
    // Overlay: pld live during the flash loop; ep.* live only after the
    // post-loop barrier. max(12288, 31616) = 31616 B.
    __shared__ union SharedU {
        unsigned short pld[4][48 * 32];          // per-wave P^T [n 48][m 32], 3KB each
        struct {
            float red[4][48][36];                // per-wave acc [n][ci 32 +4pad]
            float lred[4][48];                   // per-wave lsum per n
            unsigned short yld[32][50];          // normalized y^T [ci][n 48+2]
        } ep;
    } sh;

    const int tid  = threadIdx.x;
    const int w    = tid >> 6;
    const int lane = tid & 63;
    const int q  = lane >> 4;
    const int c  = lane & 15;
    const int sw = ((c >> 1) & 3) << 3;   // XOR swizzle on the m short-index (16B chunks)

    const int b  = blockIdx.x / 192;
    const int nb = (blockIdx.x % 192) * 48;      // block's 48 q-rows (all 4 waves)

    // Q B-frags: theta[n][ch], lane col n = c (per rt tile), k = q*8+j
    bf16x8 qf[3];
#pragma unroll
    for (int rt = 0; rt < 3; ++rt)
        qf[rt] = *(const bf16x8*)(theta + (b * NQ + nb + rt * 16 + c) * 32 + q * 8);

    // ones A-frag: row m=0 all-ones -> lanes with c==0 hold 1.0 in all k
    bf16x8 onef;
    {
        unsigned v = (c == 0) ? 0x3F803F80u : 0u;
        unsigned* op = (unsigned*)&onef;
        op[0] = v; op[1] = v; op[2] = v; op[3] = v;
    }

    const unsigned short* phiB = phi + (size_t)b * MM * 32;
    const unsigned short* gTB  = gT + (size_t)b * 32 * MM;
    unsigned short* myp = sh.pld[w];

    f32x4 acc[3][2];    // [rt n-tile][s2 ci-tile]: col=n, row=ci
    f32x4 lacc[3];      // D row0 (lanes q=0, reg0) = lsum per col n
#pragma unroll
    for (int rt = 0; rt < 3; ++rt) {
        lacc[rt] = (f32x4){0.f, 0.f, 0.f, 0.f};
#pragma unroll
        for (int s2 = 0; s2 < 2; ++s2) acc[rt][s2] = (f32x4){0.f, 0.f, 0.f, 0.f};
    }

    const int t0 = w * TPW;    // this wave's first 32-m tile
    bf16x8 kf[2], vf[2];

#define LOAD_KF(m0) do {                                                      \
    kf[0] = *(const bf16x8*)(phiB + ((m0) + c) * 32 + q * 8);                 \
    kf[1] = *(const bf16x8*)(phiB + ((m0) + 16 + c) * 32 + q * 8);            \
} while (0)

#define LOAD_VF(m0) do {                                                      \
    vf[0] = *(const bf16x8*)(gTB + c * MM + (m0) + q * 8);                    \
    vf[1] = *(const bf16x8*)(gTB + (16 + c) * MM + (m0) + q * 8);             \
} while (0)

// S(rt): 2 S-MFMAs + 8 exp2 + 4 cvt_pk + 2 ds_write_b64 (no lsum VALU adds)
#define S_STEP(rt) do {                                                      \
    _Pragma("unroll")                                                        \
    for (int mct = 0; mct < 2; ++mct) {                                      \
        f32x4 z = {0.f, 0.f, 0.f, 0.f};                                      \
        f32x4 s = __builtin_amdgcn_mfma_f32_16x16x32_bf16(kf[mct], qf[rt], z, 0, 0, 0); \
        uint2 hv = {pk2(__builtin_amdgcn_exp2f(s[0]), __builtin_amdgcn_exp2f(s[1])),    \
                    pk2(__builtin_amdgcn_exp2f(s[2]), __builtin_amdgcn_exp2f(s[3]))};   \
        *(uint2*)(myp + (((rt) * 16 + c) << 5) + ((mct * 16 + 4 * q) ^ sw)) = hv;       \
    }                                                                        \
} while (0)

// PV(rt): 1 ds_read_b128 + 2 acc-MFMAs + 1 lsum-MFMA (ones row)
#define PV_STEP(rt) do {                                                     \
    bf16x8 pf = *(const bf16x8*)(myp + (((rt) * 16 + c) << 5) + ((q * 8) ^ sw)); \
    acc[rt][0] = __builtin_amdgcn_mfma_f32_16x16x32_bf16(vf[0], pf, acc[rt][0], 0, 0, 0); \
    acc[rt][1] = __builtin_amdgcn_mfma_f32_16x16x32_bf16(vf[1], pf, acc[rt][1], 0, 0, 0); \
    lacc[rt]   = __builtin_amdgcn_mfma_f32_16x16x32_bf16(onef,  pf, lacc[rt],   0, 0, 0); \
} while (0)

    // ---- prologue: tile 0 S/exp/write ----
    LOAD_KF(t0 * 32);
    LOAD_VF(t0 * 32);
    S_STEP(0); S_STEP(1); S_STEP(2);

    // ---- steady state (R13-proven schedule) ----
    for (int mi = 1; mi < TPW; ++mi) {
        const int m0 = (t0 + mi) * 32;
        LOAD_KF(m0);                          // kf(i), consumed by S(i) below
        PV_STEP(0); PV_STEP(1); PV_STEP(2);   // P(i-1) x vf(i-1)
        LOAD_VF(m0);                          // vf(i), consumed next iter
        S_STEP(0); S_STEP(1); S_STEP(2);
    }

    // ---- epilogue: PV of last tile ----
    PV_STEP(0); PV_STEP(1); PV_STEP(2);

#undef LOAD_KF
#undef LOAD_VF
#undef S_STEP
#undef PV_STEP

    // ---- overlay safety: all pld reads done before ep.* writes ----
    __syncthreads();

    // ---- stage per-wave partial slices ----
    // lacc D row0 lives in lanes q=0 (lane<16), reg 0
    if (lane < 16) {
        sh.ep.lred[w][lane]      = lacc[0][0];
        sh.ep.lred[w][16 + lane] = lacc[1][0];
        sh.ep.lred[w][32 + lane] = lacc[2][0];
    }
#pragma unroll
    for (int rt = 0; rt < 3; ++rt)
#pragma unroll
        for (int s2 = 0; s2 < 2; ++s2)
            *(f32x4*)&sh.ep.red[w][rt * 16 + c][s2 * 16 + 4 * q] = acc[rt][s2];

    __syncthreads();

    // ---- cross-wave sum + normalize -> yld bf16 [ci][n] ----
    if (tid < 192) {
        const int n   = tid % 48;            // 48 n
        const int cig = (tid / 48) * 8;      // 8 ci values per thread
        float ls = (sh.ep.lred[0][n] + sh.ep.lred[1][n]) +
                   (sh.ep.lred[2][n] + sh.ep.lred[3][n]);
        float inv = 1.0f / ls;
        f32x4 s0 = {0.f, 0.f, 0.f, 0.f}, s1 = {0.f, 0.f, 0.f, 0.f};
#pragma unroll
        for (int ww = 0; ww < 4; ++ww) {
            s0 += *(const f32x4*)&sh.ep.red[ww][n][cig];
            s1 += *(const f32x4*)&sh.ep.red[ww][n][cig + 4];
        }
#pragma unroll
        for (int k = 0; k < 4; ++k) {
            sh.ep.yld[cig + k][n]     = (unsigned short)(pk2(s0[k] * inv, 0.f) & 0xffff);
            sh.ep.yld[cig + 4 + k][n] = (unsigned short)(pk2(s1[k] * inv, 0.f) & 0xffff);
        }
    }
    __syncthreads();

    // ---- fused out-projection: wave w -> chn rows w*16..w*16+15 ----
    {
        bf16x8 wof;
        {
            const float* wsrc = w_out + (w * 16 + c) * 32 + q * 8;
            f32x4 w0 = *(const f32x4*)wsrc;
            f32x4 w1 = *(const f32x4*)(wsrc + 4);
            unsigned* wk = (unsigned*)&wof;
            wk[0] = pk2(w0[0], w0[1]); wk[1] = pk2(w0[2], w0[3]);
            wk[2] = pk2(w1[0], w1[1]); wk[3] = pk2(w1[2], w1[3]);
        }
#pragma unroll
        for (int nt = 0; nt < 3; ++nt) {
            bf16x8 yf;
            unsigned short* yp = (unsigned short*)&yf;
#pragma unroll
            for (int j = 0; j < 8; ++j)
                yp[j] = sh.ep.yld[q * 8 + j][nt * 16 + c];
            f32x4 z = {0.f, 0.f, 0.f, 0.f};
            f32x4 o = __builtin_amdgcn_mfma_f32_16x16x32_bf16(wof, yf, z, 0, 0, 0);
#pragma unroll
            for (int r = 0; r < 4; ++r) {
                const int chn = w * 16 + 4 * q + r;
                const size_t addr = (size_t)(b * 64 + chn) * NQ + nb + nt * 16 + c;
                out[addr] = o[r] + b_out[chn] + x[addr];
            }
        }
    }
}

extern "C" void kernel_launch(void* const* d_in, const int* in_sizes, int n_in,
                              void* d_out, int out_size, void* d_ws, size_t ws_size,
                              hipStream_t stream) {
    const float* x       = (const float*)d_in[0];
    const float* w_theta = (const float*)d_in[1];
    const float* b_theta = (const float*)d_in[2];
    const float* w_phi   = (const float*)d_in[3];
    const float* b_phi   = (const float*)d_in[4];
    const float* w_g     = (const float*)d_in[5];
    const float* b_g     = (const float*)d_in[6];
    const float* w_out   = (const float*)d_in[7];
    const float* b_out   = (const float*)d_in[8];
    float* out = (float*)d_out;

    // ws layout (bytes):
    //   theta bf16 [4][9216][32] : 2,359,296
    //   phi   bf16 [4][4608][32] : 1,179,648
    //   gT    bf16 [4][32][4608] : 1,179,648
    unsigned short* theta = (unsigned short*)d_ws;
    unsigned short* phi   = theta + 4 * NQ * 32;
    unsigned short* gT    = phi + 4 * MM * 32;

    proj_kernel<<<576, 128, 0, stream>>>(x, w_theta, b_theta, w_phi, b_phi,
                                         w_g, b_g, theta, phi, gT);
    attn_kernel<<<768, 256, 0, stream>>>(theta, phi, gT, w_out, b_out, x, out);
}